// Round 5
// baseline (3019.228 us; speedup 1.0000x reference)
//
#include <hip/hip_runtime.h>
#include <hip/hip_cooperative_groups.h>

namespace cg = cooperative_groups;

// Jacobi pseudo-timestepping of -div(exp(u) grad p) = f on a 1024x1024 grid.
// Persistent cooperative kernel: each block owns a 32x32 tile; coefficients and
// the p-interior stay in LDS for all 100 steps. Per 4-step group only the
// width-4 halo ring is exchanged through global ping-pong buffers + grid.sync().
//
// p_new = A*(p_xp + p_yp) + Bx*p_xm + By*p_ym + D
//   A = eu/den, Bx = eu_xm/den, By = eu_ym/den, D = h^2 f/den, den = 2eu+eu_xm+eu_ym
// BC: p[:,0] = i*h, p[:,N-1] = 1-i*h;  edge-replicate in x (rows).
// Out-of-grid halo cells evaluate the stencil at their CLAMPED position, which
// keeps them exact mirror copies of edge rows (edge-replicate) by induction.

#define GN 1024
#define TT 32
#define KK 4
constexpr int S  = TT + 2 * KK;       // 40: staged p tile
constexpr int CS = TT + 2 * KK - 2;   // 38: coefficient tile
constexpr int NN = GN * GN;

__global__ __launch_bounds__(256) void gw_pre(const float* __restrict__ u,
                                              const float* __restrict__ f,
                                              float4* __restrict__ C4,
                                              float* __restrict__ p1) {
    int idx = blockIdx.x * 256 + threadIdx.x;
    int i = idx >> 10;
    int j = idx & (GN - 1);
    const float h = 1.0f / (GN - 1);

    float e   = expf(u[idx]);
    float exm = (i > 0) ? expf(u[idx - GN]) : e;   // edge-replicate row 0
    float eym = (j > 0) ? expf(u[idx - 1])  : e;   // edge-replicate col 0
    float rd  = 1.0f / (2.0f * e + exm + eym);

    float d = h * h * f[idx] * rd;
    C4[idx] = make_float4(e * rd, exm * rd, eym * rd, d);

    // step 1 from p0 = 0: interior is just D, BC columns overridden
    float p;
    if (j == 0)            p = i * h;
    else if (j == GN - 1)  p = 1.0f - i * h;
    else                   p = d;
    p1[idx] = p;
}

__global__ __launch_bounds__(256, 4) void gw_persist(float* __restrict__ pA,
                                                     float* __restrict__ pB,
                                                     const float4* __restrict__ C4,
                                                     float* __restrict__ out) {
    __shared__ float  buf[2][S * S];
    __shared__ float4 coef[CS * CS];

    cg::grid_group grid = cg::this_grid();
    const int tid = threadIdx.x;
    const int ti  = (blockIdx.x >> 5) * TT;
    const int tj  = (blockIdx.x & 31) * TT;
    const float h = 1.0f / (GN - 1);

    // stage coefficients ONCE (halo K-1, clamped)
    for (int t = tid; t < CS * CS; t += 256) {
        int li = t / CS, lj = t % CS;
        int gi = min(max(ti - (KK - 1) + li, 0), GN - 1);
        int gj = min(max(tj - (KK - 1) + lj, 0), GN - 1);
        coef[t] = C4[gi * GN + gj];
    }
    // stage full p tile ONCE from pA (halo K, clamped)
    for (int t = tid; t < S * S; t += 256) {
        int li = t / S, lj = t % S;
        int gi = min(max(ti - KK + li, 0), GN - 1);
        int gj = min(max(tj - KK + lj, 0), GN - 1);
        buf[0][t] = pA[gi * GN + gj];
    }
    __syncthreads();

    const bool edge = (ti == 0) | (tj == 0) | (ti + TT == GN) | (tj + TT == GN);

    int cur = 0;
    for (int g = 0; g < 25; ++g) {
        const int nsweep = (g < 24) ? 4 : 3;   // 24*4 + 3 = 99 steps (step 1 in gw_pre)

        #pragma unroll
        for (int s = 1; s <= KK; ++s) {
            if (s > nsweep) break;             // block-uniform
            const int R = S - 2 * s;
            const float* __restrict__ bp = buf[cur];
            float* __restrict__ bo = buf[cur ^ 1];
            for (int t = tid; t < R * R; t += 256) {
                int li = s + t / R, lj = s + t % R;
                float val;
                if (!edge) {
                    float4 c  = coef[(li - 1) * CS + (lj - 1)];
                    float pxm = bp[(li - 1) * S + lj];
                    float pxp = bp[(li + 1) * S + lj];
                    float pym = bp[li * S + lj - 1];
                    float pyp = bp[li * S + lj + 1];
                    val = fmaf(c.x, pxp + pyp, c.w);
                    val = fmaf(c.y, pxm, val);
                    val = fmaf(c.z, pym, val);
                } else {
                    int gi = ti - KK + li, gj = tj - KK + lj;
                    int ci = min(max(gi, 0), GN - 1);
                    int cj = min(max(gj, 0), GN - 1);
                    if (cj == 0)            val = ci * h;
                    else if (cj == GN - 1)  val = 1.0f - ci * h;
                    else {
                        int lic = li + (ci - gi), ljc = lj + (cj - gj);
                        float4 c  = coef[(lic - 1) * CS + (ljc - 1)];
                        float pxm = bp[(lic - 1) * S + ljc];
                        float pxp = bp[(lic + 1) * S + ljc];
                        float pym = bp[lic * S + ljc - 1];
                        float pyp = bp[lic * S + ljc + 1];
                        val = fmaf(c.x, pxp + pyp, c.w);
                        val = fmaf(c.y, pxm, val);
                        val = fmaf(c.z, pym, val);
                    }
                }
                bo[li * S + lj] = val;
            }
            cur ^= 1;
            __syncthreads();
        }

        // publish the 32x32 interior (final group -> d_out)
        float* dst = (g == 24) ? out : ((g & 1) ? pA : pB);
        for (int t = tid; t < TT * TT; t += 256) {
            int li = KK + (t >> 5), lj = KK + (t & 31);
            dst[(ti + (t >> 5)) * GN + (tj + (t & 31))] = buf[cur][li * S + lj];
        }
        if (g == 24) break;

        grid.sync();   // publishes visible device-wide

        // refresh halo ring (width K) from the just-published buffer;
        // interior [KK, S-KK)^2 is retained in buf[cur] (cur==0 after 4 sweeps)
        const float* src = (g & 1) ? pA : pB;
        for (int t = tid; t < S * S; t += 256) {
            int li = t / S, lj = t % S;
            if (li >= KK && li < S - KK && lj >= KK && lj < S - KK) continue;
            int gi = min(max(ti - KK + li, 0), GN - 1);
            int gj = min(max(tj - KK + lj, 0), GN - 1);
            buf[cur][t] = src[gi * GN + gj];
        }
        __syncthreads();
    }
}

extern "C" void kernel_launch(void* const* d_in, const int* in_sizes, int n_in,
                              void* d_out, int out_size, void* d_ws, size_t ws_size,
                              hipStream_t stream) {
    const float* u = (const float*)d_in[0];
    const float* f = (const float*)d_in[1];
    float* out = (float*)d_out;

    float*  ws = (float*)d_ws;
    float4* C4 = (float4*)ws;                       // 16 MB packed coefficients
    float*  pA = ws + (size_t)4 * NN;               // 4 MB ping
    float*  pB = ws + (size_t)5 * NN;               // 4 MB pong

    dim3 gridE(NN / 256), block(256);

    // step 1 (+ coefficient pack) -> pA
    gw_pre<<<gridE, block, 0, stream>>>(u, f, C4, pA);

    // steps 2..100 in one persistent cooperative kernel
    void* args[] = {(void*)&pA, (void*)&pB, (void*)&C4, (void*)&out};
    hipLaunchCooperativeKernel((const void*)gw_persist, dim3(1024), dim3(256),
                               args, 0, stream);
}

// Round 8
// 499.954 us; speedup vs baseline: 6.0390x; 6.0390x over previous
//
#include <hip/hip_runtime.h>

// Jacobi pseudo-timestepping of -div(exp(u) grad p) = f on a 1024x1024 grid,
// temporally blocked: K steps fused per kernel in LDS (K=8 main, K=3 tail).
//
// p_new = A*(p_xp + p_yp) + Bx*p_xm + By*p_ym + D
//   A = eu/den, Bx = eu_xm/den, By = eu_ym/den, D = h^2 f/den, den = 2eu+eu_xm+eu_ym
// Coefficients sum to 1 exactly: By = 1 - 2A - Bx  (saves a 4th coefficient plane).
// BC: p[:,0] = i*h, p[:,N-1] = 1-i*h;  edge-replicate in x (rows).
//
// Per block: stage p (T+2K)^2 with halo K (clamped) and coef planes A,Bx,D with
// halo K-1, run K shrinking sweeps in LDS ping-pong, write the 32x32 interior.
// Out-of-grid halo cells evaluate the stencil at their CLAMPED position, which
// keeps them exact mirror copies of the edge rows (edge-replicate) by induction.

#define GN 1024
#define TT 32
constexpr int NN = GN * GN;

__global__ __launch_bounds__(256) void gw_pre(const float* __restrict__ u,
                                              const float* __restrict__ f,
                                              float* __restrict__ Ap,
                                              float* __restrict__ Bxp,
                                              float* __restrict__ Dp,
                                              float* __restrict__ p1) {
    int idx = blockIdx.x * 256 + threadIdx.x;
    int i = idx >> 10;
    int j = idx & (GN - 1);
    const float h = 1.0f / (GN - 1);

    float e   = expf(u[idx]);
    float exm = (i > 0) ? expf(u[idx - GN]) : e;   // edge-replicate row 0
    float eym = (j > 0) ? expf(u[idx - 1])  : e;   // edge-replicate col 0
    float rd  = 1.0f / (2.0f * e + exm + eym);

    Ap[idx]  = e * rd;
    Bxp[idx] = exm * rd;
    float d  = h * h * f[idx] * rd;
    Dp[idx]  = d;

    // step 1 from p0 = 0: interior is just D, BC columns overridden
    float p;
    if (j == 0)            p = i * h;
    else if (j == GN - 1)  p = 1.0f - i * h;
    else                   p = d;
    p1[idx] = p;
}

template <int K>
__global__ __launch_bounds__(256) void gw_fused(const float* __restrict__ pin,
                                                float* __restrict__ pout,
                                                const float* __restrict__ Ap,
                                                const float* __restrict__ Bxp,
                                                const float* __restrict__ Dp) {
    constexpr int S  = TT + 2 * K;       // staged p tile (48 for K=8)
    constexpr int CS = TT + 2 * K - 2;   // coefficient tile (46 for K=8)

    __shared__ float buf[2][S * S];
    __shared__ float cA[CS * CS];
    __shared__ float cB[CS * CS];
    __shared__ float cD[CS * CS];

    const int tid = threadIdx.x;
    const int ti  = (blockIdx.x >> 5) * TT;   // 32x32 grid of tiles
    const int tj  = (blockIdx.x & 31) * TT;
    const float h = 1.0f / (GN - 1);

    // stage p with halo K (clamped = edge replicate; BC columns already hold BC)
    for (int t = tid; t < S * S; t += 256) {
        int li = t / S, lj = t % S;
        int gi = min(max(ti - K + li, 0), GN - 1);
        int gj = min(max(tj - K + lj, 0), GN - 1);
        buf[0][t] = pin[gi * GN + gj];
    }
    // stage coefficient planes with halo K-1 (clamped)
    for (int t = tid; t < CS * CS; t += 256) {
        int li = t / CS, lj = t % CS;
        int gi = min(max(ti - (K - 1) + li, 0), GN - 1);
        int gj = min(max(tj - (K - 1) + lj, 0), GN - 1);
        int g  = gi * GN + gj;
        cA[t] = Ap[g];
        cB[t] = Bxp[g];
        cD[t] = Dp[g];
    }
    __syncthreads();

    const bool edge = (ti == 0) | (tj == 0) | (ti + TT == GN) | (tj + TT == GN);

    int cur = 0;
    #pragma unroll
    for (int s = 1; s <= K; ++s) {
        const int R = S - 2 * s;   // compile-time per unrolled iteration
        const float* __restrict__ bp = buf[cur];
        float* __restrict__ bo = buf[cur ^ 1];
        for (int t = tid; t < R * R; t += 256) {
            int li = s + t / R, lj = s + t % R;
            float val;
            if (!edge) {
                int c = (li - 1) * CS + (lj - 1);
                float a  = cA[c];
                float bx = cB[c];
                float by = 1.0f - bx - 2.0f * a;
                float pxm = bp[(li - 1) * S + lj];
                float pxp = bp[(li + 1) * S + lj];
                float pym = bp[li * S + lj - 1];
                float pyp = bp[li * S + lj + 1];
                val = fmaf(a, pxp + pyp, cD[c]);
                val = fmaf(bx, pxm, val);
                val = fmaf(by, pym, val);
            } else {
                int gi = ti - K + li, gj = tj - K + lj;
                int ci = min(max(gi, 0), GN - 1);
                int cj = min(max(gj, 0), GN - 1);
                if (cj == 0)            val = ci * h;
                else if (cj == GN - 1)  val = 1.0f - ci * h;
                else {
                    int lic = li + (ci - gi), ljc = lj + (cj - gj);
                    int c = (lic - 1) * CS + (ljc - 1);
                    float a  = cA[c];
                    float bx = cB[c];
                    float by = 1.0f - bx - 2.0f * a;
                    float pxm = bp[(lic - 1) * S + ljc];
                    float pxp = bp[(lic + 1) * S + ljc];
                    float pym = bp[lic * S + ljc - 1];
                    float pyp = bp[lic * S + ljc + 1];
                    val = fmaf(a, pxp + pyp, cD[c]);
                    val = fmaf(bx, pxm, val);
                    val = fmaf(by, pym, val);
                }
            }
            bo[li * S + lj] = val;
        }
        cur ^= 1;
        __syncthreads();
    }

    // write the T x T interior
    for (int t = tid; t < TT * TT; t += 256) {
        int li = K + (t >> 5), lj = K + (t & 31);
        int gi = ti + (t >> 5), gj = tj + (t & 31);
        pout[gi * GN + gj] = buf[cur][li * S + lj];
    }
}

extern "C" void kernel_launch(void* const* d_in, const int* in_sizes, int n_in,
                              void* d_out, int out_size, void* d_ws, size_t ws_size,
                              hipStream_t stream) {
    const float* u = (const float*)d_in[0];
    const float* f = (const float*)d_in[1];
    float* out = (float*)d_out;

    float* ws  = (float*)d_ws;
    float* Ap  = ws;                        // 4 MB each: A, Bx, D planes
    float* Bxp = ws + (size_t)NN;
    float* Dp  = ws + (size_t)2 * NN;
    float* pA  = ws + (size_t)3 * NN;       // 4 MB ping (d_out is the pong)

    dim3 gridE(NN / 256), block(256);
    dim3 gridT(1024);  // 32x32 tiles of 32x32

    // step 1 (+ coefficient planes) -> pA
    gw_pre<<<gridE, block, 0, stream>>>(u, f, Ap, Bxp, Dp, pA);

    // steps 2..97: 12 fused K=8 kernels; steps 98..100: one K=3 kernel.
    // 13 launches; ping-pong arranged so the final write lands in d_out.
    float* src = pA;
    float* dst = out;
    for (int k = 0; k < 12; ++k) {
        gw_fused<8><<<gridT, block, 0, stream>>>(src, dst, Ap, Bxp, Dp);
        float* t = src; src = dst; dst = t;
    }
    gw_fused<3><<<gridT, block, 0, stream>>>(src, dst, Ap, Bxp, Dp);
}

// Round 10
// 356.524 us; speedup vs baseline: 8.4685x; 1.4023x over previous
//
#include <hip/hip_runtime.h>
#include <hip/hip_fp16.h>

// Jacobi pseudo-timestepping of -div(exp(u) grad p) = f on a 1024x1024 grid.
// Temporal blocking K=9: 99 steps = 11 fused launches x 9 sweeps (step 1 folded
// into the pre/pack kernel). Occupancy rule learned in R8: LDS/block must stay
// <= 40 KB so the 1024-block grid fits 4 blocks/CU in ONE pass.
//
// p_new = A*(p_xp + p_yp) + Bx*p_xm + By*p_ym + D,  By = 1 - Bx - 2A (fp32,
// row-sum exactly 1). Coefficients stored block-packed in ws as fp16:
// half2(A,Bx) + half(D) = 6 B/cell -> LDS 33.0 KB/block -> 4 blocks/CU.
// Staging of coef tiles is pure contiguous uint4 streams (no address math).
// BC: p[:,0] = i*h, p[:,N-1] = 1-i*h; edge-replicate in x. Out-of-grid halo
// cells evaluate at their CLAMPED position (keeps exact mirrors by induction).

#define GN 1024
#define TT 32
#define KK 9
constexpr int S  = TT + 2 * KK;     // 50: p tile
constexpr int CS = S - 2;           // 48: coef tile
constexpr int CC = CS * CS;         // 2304 coef cells
constexpr int NN = GN * GN;

// One block per 32x32 tile: computes + packs this tile's coefficient halo tile
// (clamped duplication) and writes step-1 p into its interior partition.
__global__ __launch_bounds__(256) void gw_pre(const float* __restrict__ u,
                                              const float* __restrict__ f,
                                              __half2* __restrict__ pAB,
                                              __half*  __restrict__ pD,
                                              float* __restrict__ p1) {
    const int b  = blockIdx.x;
    const int ti = (b >> 5) * TT, tj = (b & 31) * TT;
    const float h = 1.0f / (GN - 1);

    for (int t = threadIdx.x; t < CC; t += 256) {
        int ci = t / CS, cj = t % CS;
        int gi = min(max(ti - (KK - 1) + ci, 0), GN - 1);
        int gj = min(max(tj - (KK - 1) + cj, 0), GN - 1);
        int g  = gi * GN + gj;
        float e   = expf(u[g]);
        float exm = (gi > 0) ? expf(u[g - GN]) : e;   // edge-replicate row 0
        float eym = (gj > 0) ? expf(u[g - 1])  : e;   // edge-replicate col 0
        float rd  = 1.0f / (2.0f * e + exm + eym);
        float a = e * rd, bx = exm * rd;
        float d = h * h * f[g] * rd;

        pAB[(size_t)b * CC + t] = __floats2half2_rn(a, bx);
        pD [(size_t)b * CC + t] = __float2half(d);

        // step 1 from p0 = 0 on this block's own interior partition
        if (ci >= (KK - 1) && ci < (KK - 1) + TT &&
            cj >= (KK - 1) && cj < (KK - 1) + TT) {
            float p;
            if (gj == 0)           p = gi * h;
            else if (gj == GN - 1) p = 1.0f - gi * h;
            else                   p = d;
            p1[g] = p;
        }
    }
}

__global__ __launch_bounds__(256) void gw_fused(const float* __restrict__ pin,
                                                float* __restrict__ pout,
                                                const __half2* __restrict__ pAB,
                                                const __half*  __restrict__ pD) {
    __shared__ float buf[2][S * S];                       // 20000 B
    __shared__ __align__(16) __half2 cAB[CC];             //  9216 B
    __shared__ __align__(16) __half  cD[CC];              //  4608 B

    const int tid = threadIdx.x;
    const int b   = blockIdx.x;
    const int ti  = (b >> 5) * TT;
    const int tj  = (b & 31) * TT;
    const float h = 1.0f / (GN - 1);

    // coef staging: pure contiguous uint4 streams
    {
        const uint4* gAB = (const uint4*)(pAB + (size_t)b * CC);  // 576 uint4
        uint4* sAB = (uint4*)cAB;
        for (int t = tid; t < CC / 4; t += 256) sAB[t] = gAB[t];
        const uint4* gD = (const uint4*)(pD + (size_t)b * CC);    // 288 uint4
        uint4* sD = (uint4*)cD;
        for (int t = tid; t < CC / 8; t += 256) sD[t] = gD[t];
    }
    // p staging with halo K (clamped = edge replicate)
    for (int t = tid; t < S * S; t += 256) {
        int li = t / S, lj = t % S;
        int gi = min(max(ti - KK + li, 0), GN - 1);
        int gj = min(max(tj - KK + lj, 0), GN - 1);
        buf[0][t] = pin[gi * GN + gj];
    }
    __syncthreads();

    const bool edge = (ti == 0) | (tj == 0) | (ti + TT == GN) | (tj + TT == GN);

    int cur = 0;
    #pragma unroll
    for (int s = 1; s <= KK; ++s) {
        const int R = S - 2 * s;   // compile-time per unrolled iteration
        const float* __restrict__ bp = buf[cur];
        float* __restrict__ bo = buf[cur ^ 1];
        for (int t = tid; t < R * R; t += 256) {
            int li = s + t / R, lj = s + t % R;
            float val;
            if (!edge) {
                int c = (li - 1) * CS + (lj - 1);
                __half2 ab = cAB[c];
                float a  = __low2float(ab);
                float bx = __high2float(ab);
                float by = 1.0f - bx - 2.0f * a;
                float d  = __half2float(cD[c]);
                float pxm = bp[(li - 1) * S + lj];
                float pxp = bp[(li + 1) * S + lj];
                float pym = bp[li * S + lj - 1];
                float pyp = bp[li * S + lj + 1];
                val = fmaf(a, pxp + pyp, d);
                val = fmaf(bx, pxm, val);
                val = fmaf(by, pym, val);
            } else {
                int gi = ti - KK + li, gj = tj - KK + lj;
                int ci = min(max(gi, 0), GN - 1);
                int cj = min(max(gj, 0), GN - 1);
                if (cj == 0)            val = ci * h;
                else if (cj == GN - 1)  val = 1.0f - ci * h;
                else {
                    int lic = li + (ci - gi), ljc = lj + (cj - gj);
                    int c = (lic - 1) * CS + (ljc - 1);
                    __half2 ab = cAB[c];
                    float a  = __low2float(ab);
                    float bx = __high2float(ab);
                    float by = 1.0f - bx - 2.0f * a;
                    float d  = __half2float(cD[c]);
                    float pxm = bp[(lic - 1) * S + ljc];
                    float pxp = bp[(lic + 1) * S + ljc];
                    float pym = bp[lic * S + ljc - 1];
                    float pyp = bp[lic * S + ljc + 1];
                    val = fmaf(a, pxp + pyp, d);
                    val = fmaf(bx, pxm, val);
                    val = fmaf(by, pym, val);
                }
            }
            bo[li * S + lj] = val;
        }
        cur ^= 1;
        __syncthreads();
    }

    // write the 32x32 interior (cur == 1 after 9 sweeps)
    for (int t = tid; t < TT * TT; t += 256) {
        int li = KK + (t >> 5), lj = KK + (t & 31);
        pout[(ti + (t >> 5)) * GN + (tj + (t & 31))] = buf[cur][li * S + lj];
    }
}

extern "C" void kernel_launch(void* const* d_in, const int* in_sizes, int n_in,
                              void* d_out, int out_size, void* d_ws, size_t ws_size,
                              hipStream_t stream) {
    const float* u = (const float*)d_in[0];
    const float* f = (const float*)d_in[1];
    float* out = (float*)d_out;

    // ws layout: packed AB (9.44 MB) | packed D (4.72 MB) | pA ping (4 MB)
    __half2* pAB = (__half2*)d_ws;
    __half*  pD  = (__half*)((char*)d_ws + (size_t)1024 * CC * 4);
    float*   pA  = (float*)((char*)d_ws + (size_t)1024 * CC * 6);

    dim3 gridT(1024), block(256);

    // coefficient pack + step 1 -> pA
    gw_pre<<<gridT, block, 0, stream>>>(u, f, pAB, pD, pA);

    // steps 2..100: 11 fused K=9 dispatches; odd count -> final lands in d_out
    float* src = pA;
    float* dst = out;
    for (int k = 0; k < 11; ++k) {
        gw_fused<<<gridT, block, 0, stream>>>(src, dst, pAB, pD);
        float* t = src; src = dst; dst = t;
    }
}

// Round 12
// 259.643 us; speedup vs baseline: 11.6284x; 1.3731x over previous
//
#include <hip/hip_runtime.h>
#include <hip/hip_fp16.h>

// Jacobi pseudo-timestepping of -div(exp(u) grad p) = f on a 1024x1024 grid.
// K=9 temporal blocking: 99 steps = 11 fused launches x 9 sweeps.
// R10 lesson: sweeps were VALU-bound (remap + converts + branches each sweep).
// This version: FIXED cell->thread mapping (2304 cells = 9/thread exactly),
// all addresses + fp32 coefficients precomputed into REGISTERS once per
// dispatch; BCs and edge-replication encoded into coefs/addresses
// (a=bx=by=0, d=BCval). Sweep inner loop = 4 ds_read(imm) + 3 fma + 1 ds_write,
// no branches, no address math. Full ring-1 tile computed every sweep (garbage
// front moves inward 1 ring/sweep; 32x32 interior after 9 sweeps is exact).
// LDS = 2 x 2500 fp32 = 20 KB -> 4 blocks/CU. Coef regs ~63 -> no spill.

#define GN 1024
#define TT 32
#define KK 9
constexpr int S  = TT + 2 * KK;     // 50: p tile
constexpr int SS = S * S;           // 2500
constexpr int CS = S - 2;           // 48: coef tile
constexpr int CC = CS * CS;         // 2304 = 9 * 256 exactly
constexpr int NN = GN * GN;

// One block per 32x32 tile: packs this tile's fp16 coefficient halo tile
// (clamped duplication) and writes step-1 p into its interior partition.
__global__ __launch_bounds__(256) void gw_pre(const float* __restrict__ u,
                                              const float* __restrict__ f,
                                              __half2* __restrict__ pAB,
                                              __half*  __restrict__ pD,
                                              float* __restrict__ p1) {
    const int b  = blockIdx.x;
    const int ti = (b >> 5) * TT, tj = (b & 31) * TT;
    const float h = 1.0f / (GN - 1);

    for (int t = threadIdx.x; t < CC; t += 256) {
        int ci = t / CS, cj = t % CS;
        int gi = min(max(ti - (KK - 1) + ci, 0), GN - 1);
        int gj = min(max(tj - (KK - 1) + cj, 0), GN - 1);
        int g  = gi * GN + gj;
        float e   = expf(u[g]);
        float exm = (gi > 0) ? expf(u[g - GN]) : e;   // edge-replicate row 0
        float eym = (gj > 0) ? expf(u[g - 1])  : e;   // edge-replicate col 0
        float rd  = 1.0f / (2.0f * e + exm + eym);
        float a = e * rd, bx = exm * rd;
        float d = h * h * f[g] * rd;

        pAB[(size_t)b * CC + t] = __floats2half2_rn(a, bx);
        pD [(size_t)b * CC + t] = __float2half(d);

        // step 1 from p0 = 0 on this block's own interior partition
        if (ci >= (KK - 1) && ci < (KK - 1) + TT &&
            cj >= (KK - 1) && cj < (KK - 1) + TT) {
            float p;
            if (gj == 0)           p = gi * h;
            else if (gj == GN - 1) p = 1.0f - gi * h;
            else                   p = d;
            p1[g] = p;
        }
    }
}

__global__ __launch_bounds__(256, 4) void gw_fused(const float* __restrict__ pin,
                                                   float* __restrict__ pout,
                                                   const __half2* __restrict__ pAB,
                                                   const __half*  __restrict__ pD) {
    __shared__ float buf[2 * SS];   // 20000 B: [0,SS) ping, [SS,2SS) pong

    const int tid = threadIdx.x;
    const int b   = blockIdx.x;
    const int ti  = (b >> 5) * TT;
    const int tj  = (b & 31) * TT;
    const float h = 1.0f / (GN - 1);

    // ---- stage p with halo K (clamped = edge replicate) ----
    #pragma unroll
    for (int k = 0; k < 10; ++k) {
        int t = tid + 256 * k;
        if (t < SS) {
            int li = t / S, lj = t % S;
            int gi = min(max(ti - KK + li, 0), GN - 1);
            int gj = min(max(tj - KK + lj, 0), GN - 1);
            buf[t] = pin[gi * GN + gj];
        }
    }

    // ---- per-cell invariants -> registers (9 cells/thread, exact) ----
    int   nxm[9], nym[9], wr[9];
    float ca[9], cbx[9], cby[9], cd[9];
    #pragma unroll
    for (int k = 0; k < 9; ++k) {
        int c  = tid + 256 * k;          // cell in [0, 2304)
        int li = 1 + c / CS, lj = 1 + c % CS;
        int gi = ti - KK + li, gj = tj - KK + lj;
        int ci = min(max(gi, 0), GN - 1), cj = min(max(gj, 0), GN - 1);
        int lic = li + (ci - gi), ljc = lj + (cj - gj);   // clamped eval pos

        nxm[k] = (lic - 1) * S + ljc;    // pxm; pxp = +2S (imm)
        nym[k] = lic * S + (ljc - 1);    // pym; pyp = +2  (imm)
        wr[k]  = li * S + lj;            // own write slot

        int cc = (lic - 1) * CS + (ljc - 1);
        __half2 ab = pAB[(size_t)b * CC + cc];
        float a  = __low2float(ab);
        float bx = __high2float(ab);
        float d  = __half2float(pD[(size_t)b * CC + cc]);
        float by = 1.0f - bx - 2.0f * a;
        if (cj == 0)           { a = 0.f; bx = 0.f; by = 0.f; d = ci * h; }
        else if (cj == GN - 1) { a = 0.f; bx = 0.f; by = 0.f; d = 1.0f - ci * h; }
        ca[k] = a; cbx[k] = bx; cby[k] = by; cd[k] = d;
    }
    __syncthreads();

    // ---- 9 sweeps, fully unrolled: branch-free, address-math-free ----
    #pragma unroll
    for (int s = 1; s <= KK; ++s) {
        const int RO = (s & 1) ? 0 : SS;   // compile-time after unroll
        const int WO = (s & 1) ? SS : 0;
        #pragma unroll
        for (int k = 0; k < 9; ++k) {
            float pxm = buf[RO + nxm[k]];
            float pxp = buf[RO + nxm[k] + 2 * S];
            float pym = buf[RO + nym[k]];
            float pyp = buf[RO + nym[k] + 2];
            float v = fmaf(ca[k], pxp + pyp, cd[k]);
            v = fmaf(cbx[k], pxm, v);
            v = fmaf(cby[k], pym, v);
            buf[WO + wr[k]] = v;
        }
        __syncthreads();
    }

    // ---- write the 32x32 interior (final data in pong: offset SS) ----
    #pragma unroll
    for (int k = 0; k < 4; ++k) {
        int t = tid + 256 * k;
        int r = t >> 5, cdx = t & 31;
        pout[(ti + r) * GN + (tj + cdx)] = buf[SS + (KK + r) * S + (KK + cdx)];
    }
}

extern "C" void kernel_launch(void* const* d_in, const int* in_sizes, int n_in,
                              void* d_out, int out_size, void* d_ws, size_t ws_size,
                              hipStream_t stream) {
    const float* u = (const float*)d_in[0];
    const float* f = (const float*)d_in[1];
    float* out = (float*)d_out;

    // ws layout: packed AB (9.44 MB) | packed D (4.72 MB) | pA ping (4 MB)
    __half2* pAB = (__half2*)d_ws;
    __half*  pD  = (__half*)((char*)d_ws + (size_t)1024 * CC * 4);
    float*   pA  = (float*)((char*)d_ws + (size_t)1024 * CC * 6);

    dim3 gridT(1024), block(256);

    // coefficient pack + step 1 -> pA
    gw_pre<<<gridT, block, 0, stream>>>(u, f, pAB, pD, pA);

    // steps 2..100: 11 fused K=9 dispatches; odd count -> final lands in d_out
    float* src = pA;
    float* dst = out;
    for (int k = 0; k < 11; ++k) {
        gw_fused<<<gridT, block, 0, stream>>>(src, dst, pAB, pD);
        float* t = src; src = dst; dst = t;
    }
}